// Round 2
// baseline (385.261 us; speedup 1.0000x reference)
//
#include <hip/hip_runtime.h>
#include <math.h>

#define BATCH 16384
#define N_CTX 10
#define N_NEG 20
#define DIM 300            // 64 float4 (256 floats) + 44-float tail
#define WAVES_PER_BLOCK 4
#define ELEMS_PER_WAVE 2
#define NBLOCKS (BATCH / (WAVES_PER_BLOCK * ELEMS_PER_WAVE))   // 2048

// log(sigmoid(x)): degree-4 series around 0 (|err|<1e-5 for |x|<0.5),
// exact stable form as fallback. Scores here are O(1e-3) by construction.
__device__ __forceinline__ float log_sigmoid_f(float x) {
    float ax = fabsf(x);
    if (ax < 0.5f) {
        float x2 = x * x;
        return -0.6931471805599453f + 0.5f * x + x2 * (-0.125f + x2 * (1.0f / 192.0f));
    }
    return fminf(x, 0.0f) - log1pf(__expf(-ax));
}

__device__ __forceinline__ float dot4(float4 a, float4 b) {
    return a.x * b.x + a.y * b.y + a.z * b.z + a.w * b.w;
}

// min waves/EU = 3 -> VGPR cap ~170: lets the next-element prefetch stay in regs
__global__ __launch_bounds__(256, 3) void cbow_loss_kernel(
    const int* __restrict__ context,     // [B, N_CTX]
    const int* __restrict__ center,      // [B]
    const int* __restrict__ negatives,   // [B, N_NEG]
    const float* __restrict__ ctx_w,     // [V, DIM]
    const float* __restrict__ cen_w,     // [V, DIM]
    float* __restrict__ partials)        // [NBLOCKS]
{
    const int wave = threadIdx.x >> 6;
    const int lane = threadIdx.x & 63;
    const int e0   = (blockIdx.x * WAVES_PER_BLOCK + wave) * ELEMS_PER_WAVE;

    // ---- all 62 indices (2 elements) in lane-parallel loads ----
    int ic0 = 0, in0 = 0, cen0 = 0, ic1 = 0, in1 = 0, cen1 = 0;
    if (lane < N_CTX) { ic0 = context[e0 * N_CTX + lane];
                        ic1 = context[(e0 + 1) * N_CTX + lane]; }
    if (lane == 0)    { cen0 = center[e0];
                        cen1 = center[e0 + 1]; }
    if (lane < N_NEG) { in0 = negatives[e0 * N_NEG + lane];
                        in1 = negatives[(e0 + 1) * N_NEG + lane]; }

    const bool has_tail = (lane < DIM - 256);   // 44 tail floats, lanes 0..43
    const int  voff4    = lane * 4;             // float4 slot -> element offset
    const int  vofft    = 256 + lane;           // tail element offset

    auto load_row = [&](const float* __restrict__ w, int s, float4& r4, float& rt) {
        const float* rowp = w + (size_t)s * DIM;
        r4 = *(const float4*)(rowp + voff4);
        rt = has_tail ? rowp[vofft] : 0.0f;
    };

    float4 ar[N_CTX]; float at[N_CTX];          // ctx rows (reused across elems)
    float4 nr[10];    float nt[10];             // neg group A
    float4 nr2[10];   float nt2[10];            // neg group B
    float4 c4;        float ct;                 // center row
    float parts[N_NEG + 1];

    float wloss = 0.0f;

    // ================= element 0: issue A-group (21 rows) =================
#pragma unroll
    for (int j = 0; j < N_CTX; ++j)
        load_row(ctx_w, __builtin_amdgcn_readlane(ic0, j), ar[j], at[j]);
    load_row(cen_w, __builtin_amdgcn_readlane(cen0, 0), c4, ct);
#pragma unroll
    for (int n = 0; n < 10; ++n)
        load_row(cen_w, __builtin_amdgcn_readlane(in0, n), nr[n], nt[n]);

    // ---- consume ctx -> mean0, pos score; issue neg group B ----
    {
        float4 m4 = make_float4(0.f, 0.f, 0.f, 0.f);
        float  mt = 0.f;
#pragma unroll
        for (int j = 0; j < N_CTX; ++j) {
            m4.x += ar[j].x; m4.y += ar[j].y; m4.z += ar[j].z; m4.w += ar[j].w;
            mt   += at[j];
        }
        m4.x *= 0.1f; m4.y *= 0.1f; m4.z *= 0.1f; m4.w *= 0.1f;
        mt *= 0.1f;

        parts[N_NEG] = dot4(m4, c4) + mt * ct;

#pragma unroll
        for (int n = 10; n < N_NEG; ++n)
            load_row(cen_w, __builtin_amdgcn_readlane(in0, n), nr2[n - 10], nt2[n - 10]);

#pragma unroll
        for (int n = 0; n < 10; ++n)
            parts[n] = dot4(m4, nr[n]) + mt * nt[n];
#pragma unroll
        for (int n = 10; n < N_NEG; ++n)
            parts[n] = dot4(m4, nr2[n - 10]) + mt * nt2[n - 10];
    }

    // ======= PREFETCH element 1 A-group BEFORE element-0 reduce =======
    // (these 21 gathers fly while the DS-swizzle reduction below runs)
#pragma unroll
    for (int j = 0; j < N_CTX; ++j)
        load_row(ctx_w, __builtin_amdgcn_readlane(ic1, j), ar[j], at[j]);
    load_row(cen_w, __builtin_amdgcn_readlane(cen1, 0), c4, ct);
#pragma unroll
    for (int n = 0; n < 10; ++n)
        load_row(cen_w, __builtin_amdgcn_readlane(in1, n), nr[n], nt[n]);

    // ---- element-0 reduce: level-major butterfly (pipelined DS ops) ----
    // Identical pairing tree per score as the per-score loop -> bitwise equal.
#pragma unroll
    for (int m = 32; m >= 1; m >>= 1) {
#pragma unroll
        for (int n = 0; n <= N_NEG; ++n)
            parts[n] += __shfl_xor(parts[n], m, 64);
    }
    {
        float loss = log_sigmoid_f(parts[N_NEG]);
#pragma unroll
        for (int n = 0; n < N_NEG; ++n)
            loss += log_sigmoid_f(-parts[n]);
        wloss -= loss;
    }

    // ================= element 1: consume =================
    {
        float4 m4 = make_float4(0.f, 0.f, 0.f, 0.f);
        float  mt = 0.f;
#pragma unroll
        for (int j = 0; j < N_CTX; ++j) {
            m4.x += ar[j].x; m4.y += ar[j].y; m4.z += ar[j].z; m4.w += ar[j].w;
            mt   += at[j];
        }
        m4.x *= 0.1f; m4.y *= 0.1f; m4.z *= 0.1f; m4.w *= 0.1f;
        mt *= 0.1f;

        parts[N_NEG] = dot4(m4, c4) + mt * ct;

#pragma unroll
        for (int n = 10; n < N_NEG; ++n)
            load_row(cen_w, __builtin_amdgcn_readlane(in1, n), nr2[n - 10], nt2[n - 10]);

#pragma unroll
        for (int n = 0; n < 10; ++n)
            parts[n] = dot4(m4, nr[n]) + mt * nt[n];
#pragma unroll
        for (int n = 10; n < N_NEG; ++n)
            parts[n] = dot4(m4, nr2[n - 10]) + mt * nt2[n - 10];
    }

    // ---- element-1 reduce ----
#pragma unroll
    for (int m = 32; m >= 1; m >>= 1) {
#pragma unroll
        for (int n = 0; n <= N_NEG; ++n)
            parts[n] += __shfl_xor(parts[n], m, 64);
    }
    {
        float loss = log_sigmoid_f(parts[N_NEG]);
#pragma unroll
        for (int n = 0; n < N_NEG; ++n)
            loss += log_sigmoid_f(-parts[n]);
        wloss -= loss;
    }

    // ---- block combine ----
    __shared__ float s_loss[WAVES_PER_BLOCK];
    if (lane == 0) s_loss[wave] = wloss;
    __syncthreads();
    if (threadIdx.x == 0)
        partials[blockIdx.x] = s_loss[0] + s_loss[1] + s_loss[2] + s_loss[3];
}

__global__ __launch_bounds__(256) void reduce_partials_kernel(
    const float* __restrict__ partials, float* __restrict__ out)
{
    __shared__ double smem[256];
    double acc = 0.0;
    for (int i = threadIdx.x; i < NBLOCKS; i += 256) acc += (double)partials[i];
    smem[threadIdx.x] = acc;
    __syncthreads();
    for (int s = 128; s > 0; s >>= 1) {
        if ((int)threadIdx.x < s) smem[threadIdx.x] += smem[threadIdx.x + s];
        __syncthreads();
    }
    if (threadIdx.x == 0) out[0] = (float)(smem[0] * (1.0 / (double)BATCH));
}

extern "C" void kernel_launch(void* const* d_in, const int* in_sizes, int n_in,
                              void* d_out, int out_size, void* d_ws, size_t ws_size,
                              hipStream_t stream) {
    const int*   context   = (const int*)d_in[0];
    const int*   center    = (const int*)d_in[1];
    const int*   negatives = (const int*)d_in[2];
    const float* ctx_w     = (const float*)d_in[3];
    const float* cen_w     = (const float*)d_in[4];
    float*       out       = (float*)d_out;
    float*       partials  = (float*)d_ws;   // 2048 floats = 8 KB

    cbow_loss_kernel<<<NBLOCKS, 256, 0, stream>>>(
        context, center, negatives, ctx_w, cen_w, partials);
    reduce_partials_kernel<<<1, 256, 0, stream>>>(partials, out);
}

// Round 3
// 373.988 us; speedup vs baseline: 1.0301x; 1.0301x over previous
//
#include <hip/hip_runtime.h>
#include <math.h>

#define BATCH 16384
#define N_CTX 10
#define N_NEG 20
#define DIM 300            // 64 float4 (256 floats) + 44-float tail
#define WAVES_PER_BLOCK 4
#define NBLOCKS (BATCH / WAVES_PER_BLOCK)   // 4096

// log(sigmoid(x)): degree-4 series around 0 (|err|<1e-5 for |x|<0.5),
// exact stable form as fallback. Scores here are O(1e-3) by construction.
__device__ __forceinline__ float log_sigmoid_f(float x) {
    float ax = fabsf(x);
    if (ax < 0.5f) {
        float x2 = x * x;
        return -0.6931471805599453f + 0.5f * x + x2 * (-0.125f + x2 * (1.0f / 192.0f));
    }
    return fminf(x, 0.0f) - log1pf(__expf(-ax));
}

__device__ __forceinline__ float dot4(float4 a, float4 b) {
    return a.x * b.x + a.y * b.y + a.z * b.z + a.w * b.w;
}

// Lean-VGPR version: rows gathered in groups of 5 (25 dest VGPRs in flight),
// consumed immediately; per-group level-major butterfly reduce.
// __launch_bounds__(256,8) caps VGPRs at 64 -> 8 waves/SIMD (2x round-0 TLP).
// Arithmetic order is IDENTICAL to the 299us round-0 kernel (absmax 0.0).
__global__ __launch_bounds__(256, 8) void cbow_loss_kernel(
    const int* __restrict__ context,     // [B, N_CTX]
    const int* __restrict__ center,      // [B]
    const int* __restrict__ negatives,   // [B, N_NEG]
    const float* __restrict__ ctx_w,     // [V, DIM]
    const float* __restrict__ cen_w,     // [V, DIM]
    float* __restrict__ partials)        // [NBLOCKS]
{
    const int wave = threadIdx.x >> 6;
    const int lane = threadIdx.x & 63;
    const int b    = blockIdx.x * WAVES_PER_BLOCK + wave;

    // ---- all 31 indices in 3 lane-parallel loads ----
    int ic = 0, cenI = 0, inI = 0;
    if (lane < N_CTX) ic   = context[b * N_CTX + lane];
    if (lane == 0)    cenI = center[b];
    if (lane < N_NEG) inI  = negatives[b * N_NEG + lane];

    const bool has_tail = (lane < DIM - 256);   // 44 tail floats, lanes 0..43
    const int  voff4    = lane * 4;             // float4 slot -> element offset
    const int  vofft    = 256 + lane;           // tail element offset

    float4 r4[5]; float rt[5];                  // one 5-row gather group

    auto load5 = [&](const float* __restrict__ w, int src, int base) {
#pragma unroll
        for (int j = 0; j < 5; ++j) {
            int s = __builtin_amdgcn_readlane(src, base + j);   // SGPR index
            const float* rowp = w + (size_t)s * DIM;
            r4[j] = *(const float4*)(rowp + voff4);
            rt[j] = has_tail ? rowp[vofft] : 0.0f;
        }
    };

    // ---- ctx mean: two groups of 5, summed in index order (matches round-0) ----
    float4 m4 = make_float4(0.f, 0.f, 0.f, 0.f);
    float  mt = 0.f;
    load5(ctx_w, ic, 0);
#pragma unroll
    for (int j = 0; j < 5; ++j) {
        m4.x += r4[j].x; m4.y += r4[j].y; m4.z += r4[j].z; m4.w += r4[j].w;
        mt   += rt[j];
    }
    load5(ctx_w, ic, 5);
#pragma unroll
    for (int j = 0; j < 5; ++j) {
        m4.x += r4[j].x; m4.y += r4[j].y; m4.z += r4[j].z; m4.w += r4[j].w;
        mt   += rt[j];
    }
    m4.x *= 0.1f; m4.y *= 0.1f; m4.z *= 0.1f; m4.w *= 0.1f;
    mt *= 0.1f;

    float acc;   // loss accumulator: lsig(pos) + sum lsig(-neg_n) in order

    // ---- group 0: center + negs 0..4 (6 rows in flight) ----
    {
        float4 c4; float ct;
        {
            int s = __builtin_amdgcn_readlane(cenI, 0);
            const float* crow = cen_w + (size_t)s * DIM;
            c4 = *(const float4*)(crow + voff4);
            ct = has_tail ? crow[vofft] : 0.0f;
        }
        load5(cen_w, inI, 0);

        float p[6];
        p[0] = dot4(m4, c4) + mt * ct;                  // positive score
#pragma unroll
        for (int j = 0; j < 5; ++j)
            p[1 + j] = dot4(m4, r4[j]) + mt * rt[j];    // negs 0..4

        // level-major butterfly: same XOR pairing tree as wave_reduce_sum
#pragma unroll
        for (int m = 32; m >= 1; m >>= 1) {
#pragma unroll
            for (int k = 0; k < 6; ++k)
                p[k] += __shfl_xor(p[k], m, 64);
        }
        acc = log_sigmoid_f(p[0]);
#pragma unroll
        for (int j = 0; j < 5; ++j)
            acc += log_sigmoid_f(-p[1 + j]);
    }

    // ---- groups 1..3: negs 5g..5g+4 ----
#pragma unroll
    for (int g = 1; g < 4; ++g) {
        load5(cen_w, inI, 5 * g);
        float p[5];
#pragma unroll
        for (int j = 0; j < 5; ++j)
            p[j] = dot4(m4, r4[j]) + mt * rt[j];
#pragma unroll
        for (int m = 32; m >= 1; m >>= 1) {
#pragma unroll
            for (int k = 0; k < 5; ++k)
                p[k] += __shfl_xor(p[k], m, 64);
        }
#pragma unroll
        for (int j = 0; j < 5; ++j)
            acc += log_sigmoid_f(-p[j]);
    }

    float wloss = -acc;

    // ---- block combine ----
    __shared__ float s_loss[WAVES_PER_BLOCK];
    if (lane == 0) s_loss[wave] = wloss;
    __syncthreads();
    if (threadIdx.x == 0)
        partials[blockIdx.x] = s_loss[0] + s_loss[1] + s_loss[2] + s_loss[3];
}

__global__ __launch_bounds__(256) void reduce_partials_kernel(
    const float* __restrict__ partials, float* __restrict__ out)
{
    __shared__ double smem[256];
    double acc = 0.0;
    for (int i = threadIdx.x; i < NBLOCKS; i += 256) acc += (double)partials[i];
    smem[threadIdx.x] = acc;
    __syncthreads();
    for (int s = 128; s > 0; s >>= 1) {
        if ((int)threadIdx.x < s) smem[threadIdx.x] += smem[threadIdx.x + s];
        __syncthreads();
    }
    if (threadIdx.x == 0) out[0] = (float)(smem[0] * (1.0 / (double)BATCH));
}

extern "C" void kernel_launch(void* const* d_in, const int* in_sizes, int n_in,
                              void* d_out, int out_size, void* d_ws, size_t ws_size,
                              hipStream_t stream) {
    const int*   context   = (const int*)d_in[0];
    const int*   center    = (const int*)d_in[1];
    const int*   negatives = (const int*)d_in[2];
    const float* ctx_w     = (const float*)d_in[3];
    const float* cen_w     = (const float*)d_in[4];
    float*       out       = (float*)d_out;
    float*       partials  = (float*)d_ws;   // 4096 floats = 16 KB

    cbow_loss_kernel<<<NBLOCKS, 256, 0, stream>>>(
        context, center, negatives, ctx_w, cen_w, partials);
    reduce_partials_kernel<<<1, 256, 0, stream>>>(partials, out);
}

// Round 4
// 363.171 us; speedup vs baseline: 1.0608x; 1.0298x over previous
//
#include <hip/hip_runtime.h>
#include <math.h>

#define BATCH 16384
#define N_CTX 10
#define N_NEG 20
#define DIM 300            // 64 float4 (256 floats) + 44-float tail
#define WAVES_PER_BLOCK 4
#define NBLOCKS (BATCH / WAVES_PER_BLOCK)   // 4096

// log(sigmoid(x)): degree-4 series around 0 (|err|<1e-5 for |x|<0.5),
// exact stable form as fallback. Scores here are O(1e-3) by construction.
__device__ __forceinline__ float log_sigmoid_f(float x) {
    float ax = fabsf(x);
    if (ax < 0.5f) {
        float x2 = x * x;
        return -0.6931471805599453f + 0.5f * x + x2 * (-0.125f + x2 * (1.0f / 192.0f));
    }
    return fminf(x, 0.0f) - log1pf(__expf(-ax));
}

__device__ __forceinline__ float dot4(float4 a, float4 b) {
    return a.x * b.x + a.y * b.y + a.z * b.z + a.w * b.w;
}

// Groups of 5 rows gathered then consumed; per-group level-major butterfly.
// launch_bounds(256,6) -> VGPR cap ~85: fits the ~55 live regs WITHOUT spilling
// (the (256,8)/cap-64 variant spilled: VGPR=32, WRITE_SIZE 188 MB, +80us),
// while allowing 6 waves/SIMD (~75% occupancy, 2x the unbounded version).
// Arithmetic order IDENTICAL to the verified round-3 kernel (absmax 0.0).
__global__ __launch_bounds__(256, 6) void cbow_loss_kernel(
    const int* __restrict__ context,     // [B, N_CTX]
    const int* __restrict__ center,      // [B]
    const int* __restrict__ negatives,   // [B, N_NEG]
    const float* __restrict__ ctx_w,     // [V, DIM]
    const float* __restrict__ cen_w,     // [V, DIM]
    float* __restrict__ partials)        // [NBLOCKS]
{
    const int wave = threadIdx.x >> 6;
    const int lane = threadIdx.x & 63;
    const int b    = blockIdx.x * WAVES_PER_BLOCK + wave;

    // ---- all 31 indices in 3 lane-parallel loads ----
    int ic = 0, cenI = 0, inI = 0;
    if (lane < N_CTX) ic   = context[b * N_CTX + lane];
    if (lane == 0)    cenI = center[b];
    if (lane < N_NEG) inI  = negatives[b * N_NEG + lane];

    const bool has_tail = (lane < DIM - 256);   // 44 tail floats, lanes 0..43
    const int  voff4    = lane * 4;             // float4 slot -> element offset
    const int  vofft    = 256 + lane;           // tail element offset

    float4 r4[5]; float rt[5];                  // one 5-row gather group

    auto load5 = [&](const float* __restrict__ w, int src, int base) {
#pragma unroll
        for (int j = 0; j < 5; ++j) {
            int s = __builtin_amdgcn_readlane(src, base + j);   // SGPR index
            const float* rowp = w + (size_t)s * DIM;
            r4[j] = *(const float4*)(rowp + voff4);
            rt[j] = has_tail ? rowp[vofft] : 0.0f;
        }
    };

    // ---- ctx mean: two groups of 5, summed in index order ----
    float4 m4 = make_float4(0.f, 0.f, 0.f, 0.f);
    float  mt = 0.f;
    load5(ctx_w, ic, 0);
#pragma unroll
    for (int j = 0; j < 5; ++j) {
        m4.x += r4[j].x; m4.y += r4[j].y; m4.z += r4[j].z; m4.w += r4[j].w;
        mt   += rt[j];
    }
    load5(ctx_w, ic, 5);
#pragma unroll
    for (int j = 0; j < 5; ++j) {
        m4.x += r4[j].x; m4.y += r4[j].y; m4.z += r4[j].z; m4.w += r4[j].w;
        mt   += rt[j];
    }
    m4.x *= 0.1f; m4.y *= 0.1f; m4.z *= 0.1f; m4.w *= 0.1f;
    mt *= 0.1f;

    float acc;   // loss accumulator: lsig(pos) + sum lsig(-neg_n) in order

    // ---- group 0: center + negs 0..4 (6 rows in flight) ----
    {
        float4 c4; float ct;
        {
            int s = __builtin_amdgcn_readlane(cenI, 0);
            const float* crow = cen_w + (size_t)s * DIM;
            c4 = *(const float4*)(crow + voff4);
            ct = has_tail ? crow[vofft] : 0.0f;
        }
        load5(cen_w, inI, 0);

        float p[6];
        p[0] = dot4(m4, c4) + mt * ct;                  // positive score
#pragma unroll
        for (int j = 0; j < 5; ++j)
            p[1 + j] = dot4(m4, r4[j]) + mt * rt[j];    // negs 0..4

        // level-major butterfly: same XOR pairing tree as wave_reduce_sum
#pragma unroll
        for (int m = 32; m >= 1; m >>= 1) {
#pragma unroll
            for (int k = 0; k < 6; ++k)
                p[k] += __shfl_xor(p[k], m, 64);
        }
        acc = log_sigmoid_f(p[0]);
#pragma unroll
        for (int j = 0; j < 5; ++j)
            acc += log_sigmoid_f(-p[1 + j]);
    }

    // ---- groups 1..3: negs 5g..5g+4 ----
#pragma unroll
    for (int g = 1; g < 4; ++g) {
        load5(cen_w, inI, 5 * g);
        float p[5];
#pragma unroll
        for (int j = 0; j < 5; ++j)
            p[j] = dot4(m4, r4[j]) + mt * rt[j];
#pragma unroll
        for (int m = 32; m >= 1; m >>= 1) {
#pragma unroll
            for (int k = 0; k < 5; ++k)
                p[k] += __shfl_xor(p[k], m, 64);
        }
#pragma unroll
        for (int j = 0; j < 5; ++j)
            acc += log_sigmoid_f(-p[j]);
    }

    float wloss = -acc;

    // ---- block combine ----
    __shared__ float s_loss[WAVES_PER_BLOCK];
    if (lane == 0) s_loss[wave] = wloss;
    __syncthreads();
    if (threadIdx.x == 0)
        partials[blockIdx.x] = s_loss[0] + s_loss[1] + s_loss[2] + s_loss[3];
}

__global__ __launch_bounds__(256) void reduce_partials_kernel(
    const float* __restrict__ partials, float* __restrict__ out)
{
    __shared__ double smem[256];
    double acc = 0.0;
    for (int i = threadIdx.x; i < NBLOCKS; i += 256) acc += (double)partials[i];
    smem[threadIdx.x] = acc;
    __syncthreads();
    for (int s = 128; s > 0; s >>= 1) {
        if ((int)threadIdx.x < s) smem[threadIdx.x] += smem[threadIdx.x + s];
        __syncthreads();
    }
    if (threadIdx.x == 0) out[0] = (float)(smem[0] * (1.0 / (double)BATCH));
}

extern "C" void kernel_launch(void* const* d_in, const int* in_sizes, int n_in,
                              void* d_out, int out_size, void* d_ws, size_t ws_size,
                              hipStream_t stream) {
    const int*   context   = (const int*)d_in[0];
    const int*   center    = (const int*)d_in[1];
    const int*   negatives = (const int*)d_in[2];
    const float* ctx_w     = (const float*)d_in[3];
    const float* cen_w     = (const float*)d_in[4];
    float*       out       = (float*)d_out;
    float*       partials  = (float*)d_ws;   // 4096 floats = 16 KB

    cbow_loss_kernel<<<NBLOCKS, 256, 0, stream>>>(
        context, center, negatives, ctx_w, cen_w, partials);
    reduce_partials_kernel<<<1, 256, 0, stream>>>(partials, out);
}

// Round 5
// 299.078 us; speedup vs baseline: 1.2882x; 1.2143x over previous
//
#include <hip/hip_runtime.h>
#include <math.h>

#define BATCH 16384
#define N_CTX 10
#define N_NEG 20
#define DIM 300            // 64 float4 (256 floats) + 44-float tail
#define WAVES_PER_BLOCK 4
#define NBLOCKS (BATCH / WAVES_PER_BLOCK)   // 4096

__device__ __forceinline__ float wave_reduce_sum(float v) {
#pragma unroll
    for (int m = 32; m >= 1; m >>= 1)
        v += __shfl_xor(v, m, 64);
    return v;
}

// log(sigmoid(x)): degree-4 series around 0 (|err|<1e-5 for |x|<0.5),
// exact stable form as fallback. Scores here are O(1e-3) by construction.
__device__ __forceinline__ float log_sigmoid_f(float x) {
    float ax = fabsf(x);
    if (ax < 0.5f) {
        float x2 = x * x;
        return -0.6931471805599453f + 0.5f * x + x2 * (-0.125f + x2 * (1.0f / 192.0f));
    }
    return fminf(x, 0.0f) - log1pf(__expf(-ax));
}

__device__ __forceinline__ float dot4(float4 a, float4 b) {
    return a.x * b.x + a.y * b.y + a.z * b.z + a.w * b.w;
}

// ROOFLINE NOTE (rounds 0-4): useful delivered traffic is fixed at 610 MB
// (31 rows x 1200 B x 16384; 240 MB tables ~= L3 so service is an L3/HBM mix).
// Measured delivered BW saturates at ~5 TB/s in every config (29%..88% occ,
// spill or no-spill). This kernel: 610 MB / 123 us = 4.96 TB/s = the ceiling.
// Do NOT add __launch_bounds__ min-waves (forces spills: +180..370 MB scratch,
// +70..100 us) and do NOT prefetch a 2nd element per wave (same).
__global__ __launch_bounds__(256) void cbow_loss_kernel(
    const int* __restrict__ context,     // [B, N_CTX]
    const int* __restrict__ center,      // [B]
    const int* __restrict__ negatives,   // [B, N_NEG]
    const float* __restrict__ ctx_w,     // [V, DIM]
    const float* __restrict__ cen_w,     // [V, DIM]
    float* __restrict__ partials)        // [NBLOCKS]
{
    const int wave = threadIdx.x >> 6;
    const int lane = threadIdx.x & 63;
    const int b    = blockIdx.x * WAVES_PER_BLOCK + wave;

    // ---- all 31 indices in 3 lane-parallel loads (no serial idx chain) ----
    int idx_ctx = 0, idx_cen = 0, idx_neg = 0;
    if (lane < N_CTX) idx_ctx = context[b * N_CTX + lane];
    if (lane == 0)    idx_cen = center[b];
    if (lane < N_NEG) idx_neg = negatives[b * N_NEG + lane];

    const bool has_tail = (lane < DIM - 256);   // 44 tail floats, lanes 0..43
    const int  voff4    = lane * 4;              // float4 slot -> element offset
    const int  vofft    = 256 + lane;            // tail element offset

    // ---- issue ctx rows (10), center, neg group A (10): ~21 rows in flight ----
    float4 ar[N_CTX]; float at[N_CTX];
#pragma unroll
    for (int j = 0; j < N_CTX; ++j) {
        int s = __builtin_amdgcn_readlane(idx_ctx, j);      // SGPR index
        const float* rowp = ctx_w + (size_t)s * DIM;
        ar[j] = *(const float4*)(rowp + voff4);
        at[j] = has_tail ? rowp[vofft] : 0.0f;
    }

    {
        int s = __builtin_amdgcn_readlane(idx_cen, 0);
        const float* crow = cen_w + (size_t)s * DIM;
        float4 c4 = *(const float4*)(crow + voff4);
        float  ct = has_tail ? crow[vofft] : 0.0f;

        float4 nr[10]; float nt[10];
#pragma unroll
        for (int n = 0; n < 10; ++n) {
            int sn = __builtin_amdgcn_readlane(idx_neg, n);
            const float* rowp = cen_w + (size_t)sn * DIM;
            nr[n] = *(const float4*)(rowp + voff4);
            nt[n] = has_tail ? rowp[vofft] : 0.0f;
        }

        // ---- consume ctx -> mean ----
        float4 m4 = make_float4(0.f, 0.f, 0.f, 0.f);
        float  mt = 0.f;
#pragma unroll
        for (int j = 0; j < N_CTX; ++j) {
            m4.x += ar[j].x; m4.y += ar[j].y; m4.z += ar[j].z; m4.w += ar[j].w;
            mt   += at[j];
        }
        m4.x *= 0.1f; m4.y *= 0.1f; m4.z *= 0.1f; m4.w *= 0.1f;
        mt *= 0.1f;

        float parts[N_NEG + 1];
        parts[N_NEG] = dot4(m4, c4) + mt * ct;              // positive score
#pragma unroll
        for (int n = 0; n < 10; ++n)
            parts[n] = dot4(m4, nr[n]) + mt * nt[n];

        // ---- neg group B reuses nr/nt registers ----
#pragma unroll
        for (int n = 10; n < N_NEG; ++n) {
            int sn = __builtin_amdgcn_readlane(idx_neg, n);
            const float* rowp = cen_w + (size_t)sn * DIM;
            nr[n - 10] = *(const float4*)(rowp + voff4);
            nt[n - 10] = has_tail ? rowp[vofft] : 0.0f;
        }
#pragma unroll
        for (int n = 10; n < N_NEG; ++n)
            parts[n] = dot4(m4, nr[n - 10]) + mt * nt[n - 10];

        // ---- reductions + loss ----
        float pos = wave_reduce_sum(parts[N_NEG]);
        float loss = log_sigmoid_f(pos);
#pragma unroll
        for (int n = 0; n < N_NEG; ++n) {
            float ns = wave_reduce_sum(parts[n]);
            loss += log_sigmoid_f(-ns);
        }
        loss = -loss;

        __shared__ float s_loss[WAVES_PER_BLOCK];
        if (lane == 0) s_loss[wave] = loss;
        __syncthreads();
        if (threadIdx.x == 0)
            partials[blockIdx.x] = s_loss[0] + s_loss[1] + s_loss[2] + s_loss[3];
    }
}

__global__ __launch_bounds__(256) void reduce_partials_kernel(
    const float* __restrict__ partials, float* __restrict__ out)
{
    __shared__ double smem[256];
    double acc = 0.0;
    for (int i = threadIdx.x; i < NBLOCKS; i += 256) acc += (double)partials[i];
    smem[threadIdx.x] = acc;
    __syncthreads();
    for (int s = 128; s > 0; s >>= 1) {
        if ((int)threadIdx.x < s) smem[threadIdx.x] += smem[threadIdx.x + s];
        __syncthreads();
    }
    if (threadIdx.x == 0) out[0] = (float)(smem[0] * (1.0 / (double)BATCH));
}

extern "C" void kernel_launch(void* const* d_in, const int* in_sizes, int n_in,
                              void* d_out, int out_size, void* d_ws, size_t ws_size,
                              hipStream_t stream) {
    const int*   context   = (const int*)d_in[0];
    const int*   center    = (const int*)d_in[1];
    const int*   negatives = (const int*)d_in[2];
    const float* ctx_w     = (const float*)d_in[3];
    const float* cen_w     = (const float*)d_in[4];
    float*       out       = (float*)d_out;
    float*       partials  = (float*)d_ws;   // 4096 floats = 16 KB

    cbow_loss_kernel<<<NBLOCKS, 256, 0, stream>>>(
        context, center, negatives, ctx_w, cen_w, partials);
    reduce_partials_kernel<<<1, 256, 0, stream>>>(partials, out);
}